// Round 4
// baseline (99.966 us; speedup 1.0000x reference)
//
#include <hip/hip_runtime.h>
#include <hip/hip_bf16.h>

// VoxelNeRF Raw2Alpha + Alphas2Weights — single fused kernel.
//
// One 64-lane wave per ray. Each wave locates its segment [s,e) in the sorted
// ray_id array via galloping binary search from the uniform-distribution hint
// (r*M/N), then computes lom = -softplus(density+shift)*interval, a wave-level
// segmented exclusive scan (8 elems/lane serial prefix + DPP wave scan), and
// writes weights = exp(ex)*alpha with aligned float4 stores.
// alphainv_last[r] = exp(sum lom).  No workspace, one dispatch.

#define EPL 8              // elements per lane
#define CHUNK (64 * EPL)   // 512 elements per wave iteration

__device__ __forceinline__ float wave_incl_scan(float x) {
    // inclusive add-scan across 64 lanes via DPP (pure VALU, no LDS)
    float v = x;
    v += __int_as_float(__builtin_amdgcn_update_dpp(0, __float_as_int(v), 0x111, 0xf, 0xf, true));  // row_shr:1
    v += __int_as_float(__builtin_amdgcn_update_dpp(0, __float_as_int(v), 0x112, 0xf, 0xf, true));  // row_shr:2
    v += __int_as_float(__builtin_amdgcn_update_dpp(0, __float_as_int(v), 0x114, 0xf, 0xf, true));  // row_shr:4
    v += __int_as_float(__builtin_amdgcn_update_dpp(0, __float_as_int(v), 0x118, 0xf, 0xf, true));  // row_shr:8
    v += __int_as_float(__builtin_amdgcn_update_dpp(0, __float_as_int(v), 0x142, 0xa, 0xf, false)); // row_bcast:15
    v += __int_as_float(__builtin_amdgcn_update_dpp(0, __float_as_int(v), 0x143, 0xc, 0xf, false)); // row_bcast:31
    return v;
}

// first i in [0,M] with a[i] >= key; gallop outward from hint, then binary.
__device__ __forceinline__ int lower_bound_gallop(const int* __restrict__ a,
                                                  int M, int key, int hint) {
    if (hint < 0) hint = 0;
    if (hint >= M) hint = M - 1;
    int lo, hi;
    if (a[hint] >= key) {
        int step = 32;
        hi = hint;
        lo = hint - step;
        while (lo >= 0 && a[lo] >= key) { hi = lo; step <<= 1; lo = hint - step; }
        if (lo < 0) lo = -1;
    } else {
        int step = 32;
        lo = hint;
        hi = hint + step;
        while (hi < M && a[hi] < key) { lo = hi; step <<= 1; hi = hint + step; }
        if (hi > M) hi = M;
    }
    // invariant: a[lo] < key (lo==-1 ok), a[hi] >= key (hi==M ok)
    while (hi - lo > 1) {
        const int mid = (lo + hi) >> 1;
        if (a[mid] >= key) hi = mid; else lo = mid;
    }
    return hi;
}

__global__ __launch_bounds__(256) void VoxelNeRF_fused(
    const float* __restrict__ density,
    const int*   __restrict__ ray_id,
    const float* __restrict__ shift_p,
    const float* __restrict__ interval_p,
    float* __restrict__ weights,
    float* __restrict__ alphainv_last,
    int M, int N) {
    const int wave = threadIdx.x >> 6;
    const int lane = threadIdx.x & 63;
    const int r = blockIdx.x * 4 + wave;
    if (r >= N) return;

    const int avg  = M / N;
    const int s = lower_bound_gallop(ray_id, M, r,     (int)(((long long)r * M) / N));
    const int e = lower_bound_gallop(ray_id, M, r + 1, s + avg);

    const float shift    = shift_p[0];
    const float interval = interval_p[0];

    float carry = 0.0f;                 // sum of lom over previous chunks
    const int a0 = s & ~(EPL - 1);      // 32B-aligned chunk origin

    for (int base = a0; base < e; base += CHUNK) {
        const int g = base + lane * EPL;     // this lane's group start (mult of 8)

        float x8[EPL];
        if (g < e && g + EPL <= M) {         // aligned vector load of the group
            const float4* p = reinterpret_cast<const float4*>(density + g);
            const float4 v0 = p[0];
            const float4 v1 = p[1];
            x8[0] = v0.x; x8[1] = v0.y; x8[2] = v0.z; x8[3] = v0.w;
            x8[4] = v1.x; x8[5] = v1.y; x8[6] = v1.z; x8[7] = v1.w;
        } else if (g < e) {                  // defensive tail (M not mult of 8)
            #pragma unroll
            for (int k = 0; k < EPL; ++k) {
                const int i = g + k;
                x8[k] = (i < M) ? density[i] : 0.0f;
            }
        }

        float al[EPL], pk[EPL];
        float lane_sum = 0.0f;
        #pragma unroll
        for (int k = 0; k < EPL; ++k) {
            const int i = g + k;
            float lomk = 0.0f, alk = 0.0f;
            if (i >= s && i < e) {
                const float x  = x8[k] + shift;
                const float sp = fmaxf(x, 0.0f) + __logf(1.0f + __expf(-fabsf(x)));
                lomk = -sp * interval;
                alk  = 1.0f - __expf(lomk);
            }
            al[k] = alk;
            pk[k] = lane_sum;                // exclusive-within-lane prefix
            lane_sum += lomk;
        }

        const float v_incl  = wave_incl_scan(lane_sum);
        const float base_ex = carry + (v_incl - lane_sum);   // exclusive lane base

        if (g >= s && g + EPL <= e) {        // full group: aligned vector store
            float4 w0, w1;
            w0.x = __expf(base_ex + pk[0]) * al[0];
            w0.y = __expf(base_ex + pk[1]) * al[1];
            w0.z = __expf(base_ex + pk[2]) * al[2];
            w0.w = __expf(base_ex + pk[3]) * al[3];
            w1.x = __expf(base_ex + pk[4]) * al[4];
            w1.y = __expf(base_ex + pk[5]) * al[5];
            w1.z = __expf(base_ex + pk[6]) * al[6];
            w1.w = __expf(base_ex + pk[7]) * al[7];
            float4* q = reinterpret_cast<float4*>(weights + g);
            q[0] = w0;
            q[1] = w1;
        } else if (g + EPL > s && g < e) {   // boundary group: predicated scalar
            #pragma unroll
            for (int k = 0; k < EPL; ++k) {
                const int i = g + k;
                if (i >= s && i < e) {
                    weights[i] = __expf(base_ex + pk[k]) * al[k];
                }
            }
        }

        carry += __int_as_float(__builtin_amdgcn_readlane(__float_as_int(v_incl), 63));
    }

    if (lane == 0) {
        alphainv_last[r] = __expf(carry);
    }
}

extern "C" void kernel_launch(void* const* d_in, const int* in_sizes, int n_in,
                              void* d_out, int out_size, void* d_ws, size_t ws_size,
                              hipStream_t stream) {
    const float* density    = (const float*)d_in[0];
    const int*   ray_id     = (const int*)d_in[1];
    const float* shift_p    = (const float*)d_in[2];
    const float* interval_p = (const float*)d_in[3];
    const int M = in_sizes[0];
    const int N = out_size - M;

    float* weights       = (float*)d_out;
    float* alphainv_last = (float*)d_out + M;

    const int waves_per_block = 4;
    const int blocks = (N + waves_per_block - 1) / waves_per_block;
    VoxelNeRF_fused<<<blocks, 256, 0, stream>>>(
        density, ray_id, shift_p, interval_p, weights, alphainv_last, M, N);
}

// Round 6
// 92.620 us; speedup vs baseline: 1.0793x; 1.0793x over previous
//
#include <hip/hip_runtime.h>
#include <hip/hip_bf16.h>

// VoxelNeRF Raw2Alpha + Alphas2Weights (segmented exclusive scan in log space).
//
// k1 (find_starts): streaming segment-offset pass over sorted ray_id
//     (int4-vectorized, fully coalesced) -> start[N+1] in d_ws.
// k2 (scan): one wave per ray. Lane j owns 8 consecutive elements aligned to
//     32B; aligned float4 loads/stores, per-lane serial prefix + one DPP wave
//     scan per 512-element chunk (row_shr 1/2/4/8 + row_bcast 15/31 — pure
//     VALU, no LDS). Fast __expf/__logf (abs err ~1e-7 << 5.5e-3 threshold).

#define EPL 8              // elements per lane
#define CHUNK (64 * EPL)   // 512 elements per wave iteration

__device__ __forceinline__ float wave_incl_scan(float x) {
    // inclusive add-scan across 64 lanes via DPP (pure VALU, no LDS)
    float v = x;
    v += __int_as_float(__builtin_amdgcn_update_dpp(0, __float_as_int(v), 0x111, 0xf, 0xf, true));  // row_shr:1
    v += __int_as_float(__builtin_amdgcn_update_dpp(0, __float_as_int(v), 0x112, 0xf, 0xf, true));  // row_shr:2
    v += __int_as_float(__builtin_amdgcn_update_dpp(0, __float_as_int(v), 0x114, 0xf, 0xf, true));  // row_shr:4
    v += __int_as_float(__builtin_amdgcn_update_dpp(0, __float_as_int(v), 0x118, 0xf, 0xf, true));  // row_shr:8
    v += __int_as_float(__builtin_amdgcn_update_dpp(0, __float_as_int(v), 0x142, 0xa, 0xf, false)); // row_bcast:15
    v += __int_as_float(__builtin_amdgcn_update_dpp(0, __float_as_int(v), 0x143, 0xc, 0xf, false)); // row_bcast:31
    return v;
}

__global__ void VoxelNeRF_find_starts(const int* __restrict__ ray_id,
                                      int* __restrict__ start,
                                      int M, int N) {
    const int j  = blockIdx.x * blockDim.x + threadIdx.x;
    const int i0 = j * 4;
    if (i0 >= M) return;
    const int4 v = *reinterpret_cast<const int4*>(ray_id + i0);  // M % 4 == 0
    int prev = (i0 == 0) ? -1 : ray_id[i0 - 1];
    const int ids0 = v.x, ids1 = v.y, ids2 = v.z, ids3 = v.w;
    #pragma unroll
    for (int k = 0; k < 4; ++k) {
        const int cur = (k == 0) ? ids0 : (k == 1) ? ids1 : (k == 2) ? ids2 : ids3;
        if (cur != prev) {
            for (int r = prev + 1; r <= cur; ++r) start[r] = i0 + k;
        }
        prev = cur;
    }
    if (i0 + 4 >= M) {
        for (int r = prev + 1; r <= N; ++r) start[r] = M;
    }
}

__global__ __launch_bounds__(256) void VoxelNeRF_scan(
    const float* __restrict__ density,
    const int*   __restrict__ start,
    const float* __restrict__ shift_p,
    const float* __restrict__ interval_p,
    float* __restrict__ weights,
    float* __restrict__ alphainv_last,
    int M, int N) {
    const int wave = threadIdx.x >> 6;
    const int lane = threadIdx.x & 63;
    const int r = blockIdx.x * 4 + wave;
    if (r >= N) return;

    const int s = start[r];
    const int e = start[r + 1];
    const float shift    = shift_p[0];
    const float interval = interval_p[0];

    float carry = 0.0f;                 // sum of lom over previous chunks
    const int a0 = s & ~(EPL - 1);      // 32B-aligned chunk origin

    for (int base = a0; base < e; base += CHUNK) {
        const int g = base + lane * EPL;     // this lane's group start (mult of 8)

        float x8[EPL];
        if (g < e && g + EPL <= M) {         // aligned vector load of the group
            const float4* p = reinterpret_cast<const float4*>(density + g);
            const float4 v0 = p[0];
            const float4 v1 = p[1];
            x8[0] = v0.x; x8[1] = v0.y; x8[2] = v0.z; x8[3] = v0.w;
            x8[4] = v1.x; x8[5] = v1.y; x8[6] = v1.z; x8[7] = v1.w;
        } else if (g < e) {                  // defensive tail (M not mult of 8)
            #pragma unroll
            for (int k = 0; k < EPL; ++k) {
                const int i = g + k;
                x8[k] = (i < M) ? density[i] : 0.0f;
            }
        }

        float al[EPL], pk[EPL];
        float lane_sum = 0.0f;
        #pragma unroll
        for (int k = 0; k < EPL; ++k) {
            const int i = g + k;
            float lomk = 0.0f, alk = 0.0f;
            if (i >= s && i < e) {
                const float x  = x8[k] + shift;
                const float sp = fmaxf(x, 0.0f) + __logf(1.0f + __expf(-fabsf(x)));
                lomk = -sp * interval;
                alk  = 1.0f - __expf(lomk);
            }
            al[k] = alk;
            pk[k] = lane_sum;                // exclusive-within-lane prefix
            lane_sum += lomk;
        }

        const float v_incl  = wave_incl_scan(lane_sum);
        const float base_ex = carry + (v_incl - lane_sum);   // exclusive lane base

        if (g >= s && g + EPL <= e) {        // full group: aligned vector store
            float4 w0, w1;
            w0.x = __expf(base_ex + pk[0]) * al[0];
            w0.y = __expf(base_ex + pk[1]) * al[1];
            w0.z = __expf(base_ex + pk[2]) * al[2];
            w0.w = __expf(base_ex + pk[3]) * al[3];
            w1.x = __expf(base_ex + pk[4]) * al[4];
            w1.y = __expf(base_ex + pk[5]) * al[5];
            w1.z = __expf(base_ex + pk[6]) * al[6];
            w1.w = __expf(base_ex + pk[7]) * al[7];
            float4* q = reinterpret_cast<float4*>(weights + g);
            q[0] = w0;
            q[1] = w1;
        } else if (g + EPL > s && g < e) {   // boundary group: predicated scalar
            #pragma unroll
            for (int k = 0; k < EPL; ++k) {
                const int i = g + k;
                if (i >= s && i < e) {
                    weights[i] = __expf(base_ex + pk[k]) * al[k];
                }
            }
        }

        carry += __int_as_float(__builtin_amdgcn_readlane(__float_as_int(v_incl), 63));
    }

    if (lane == 0) {
        alphainv_last[r] = __expf(carry);
    }
}

extern "C" void kernel_launch(void* const* d_in, const int* in_sizes, int n_in,
                              void* d_out, int out_size, void* d_ws, size_t ws_size,
                              hipStream_t stream) {
    const float* density    = (const float*)d_in[0];
    const int*   ray_id     = (const int*)d_in[1];
    const float* shift_p    = (const float*)d_in[2];
    const float* interval_p = (const float*)d_in[3];
    const int M = in_sizes[0];
    const int N = out_size - M;

    float* weights       = (float*)d_out;
    float* alphainv_last = (float*)d_out + M;
    int*   start         = (int*)d_ws;   // N+1 ints

    {
        const int threads = 256;
        const int elems   = (M + 3) / 4;
        const int blocks  = (elems + threads - 1) / threads;
        VoxelNeRF_find_starts<<<blocks, threads, 0, stream>>>(ray_id, start, M, N);
    }
    {
        const int waves_per_block = 4;
        const int blocks = (N + waves_per_block - 1) / waves_per_block;
        VoxelNeRF_scan<<<blocks, 256, 0, stream>>>(
            density, start, shift_p, interval_p, weights, alphainv_last, M, N);
    }
}